// Round 4
// baseline (269.973 us; speedup 1.0000x reference)
//
#include <hip/hip_runtime.h>

// ---------------- problem constants ----------------
#define BATCH   8
#define LSEQ    1048576          // 1<<20
#define KCONV   500
#define TWIN    2097             // (L-K)/K + 1
#define MROWS   16776            // BATCH*TWIN
#define MPAD    16896            // 264 * 64
#define KDIM    4000             // KCONV * C_IN
#define NDIM    256              // 2 * C_OUT
#define COUT    128
#define VOCAB   257
#define VOCABP  256              // padding row of emb (all zeros)

#define SPLITK  5
#define KCH     (KDIM / SPLITK)  // 800 k-elems per split
#define PCH     (KCH / 8)        // 100 positions per split
#define NITER   (KCH / 32)       // 25 BK=32 iterations
#define BM      64               // rows per block; BN = NDIM = 256 (full N, 64 per wave)

// ---------------- ws layout (bytes) ----------------
#define WT_OFF   0ull
#define WT_BYTES ((size_t)NDIM * KDIM * 2)                  // 2,048,000
#define EMB_OFF  (WT_OFF + WT_BYTES)
#define EMB_BYTES ((size_t)VOCAB * 8 * 2)                   // 4,112 (16B-aligned)
#define CP_OFF   (EMB_OFF + EMB_BYTES)
#define CP_BYTES ((size_t)SPLITK * NDIM * MPAD * 2)         // 43,253,760 (bf16, [kc][n][m])
#define POOL_OFF (CP_OFF + CP_BYTES)                        // 8*128 floats

typedef __attribute__((ext_vector_type(8))) __bf16 bf16x8;
typedef __attribute__((ext_vector_type(4))) float  floatx4;

__device__ inline unsigned short f2bf(float f) {
    union { float f; unsigned u; } c; c.f = f;
    return (unsigned short)((c.u + 0x7FFFu + ((c.u >> 16) & 1u)) >> 16);
}
__device__ inline unsigned pack2(float lo, float hi) {
    return (unsigned)f2bf(lo) | ((unsigned)f2bf(hi) << 16);
}
__device__ inline float bf2f(unsigned short u) {
    return __uint_as_float((unsigned)u << 16);
}

// ---------------- kernel 1: coalesced weight transpose + bf16 emb table ----------------
// One block per out-channel o: w[o][e][k] (4000 floats, contiguous) -> LDS -> Wt[o][k*8+e].
// Block 0 additionally builds embbf[257][8] (16B rows for direct A-fragment gathers).
__global__ __launch_bounds__(256) void wprep_kernel(const float* __restrict__ w1,
                                                    const float* __restrict__ w2,
                                                    const float* __restrict__ emb,
                                                    unsigned short* __restrict__ Wt,
                                                    unsigned short* __restrict__ embbf) {
    const int o   = blockIdx.x;                        // 0..255
    const int tid = threadIdx.x;
    __shared__ float tile[KDIM];                       // 16 KB
    const float* src = (o < COUT) ? (w1 + (size_t)o * KDIM)
                                  : (w2 + (size_t)(o - COUT) * KDIM);
    for (int i = tid; i < KDIM; i += 256) tile[i] = src[i];
    __syncthreads();
    unsigned short* dst = Wt + (size_t)o * KDIM;
    for (int i = tid; i < KDIM; i += 256) {
        int k = i >> 3, e = i & 7;
        dst[i] = f2bf(tile[e * KCONV + k]);            // Wt[o][k*8+e] = w[o][e][k]
    }
    if (o == 0)
        for (int i = tid; i < VOCAB * 8; i += 256) embbf[i] = f2bf(emb[i]);
}

// ---------------- kernel 2: barrier-free register-streaming fused embed+GEMM ----------------
// Cp[kc][n][m] (bf16) partial = A_chunk[MPAD][800] x Wt_chunk^T
// No LDS, no __syncthreads. Each wave: 64 m-rows x 64 n-cols, 25 BK=32 iterations.
// A-frag = one 16B gather/lane from embbf (L1-resident 4KB table); x prefetched 2 iters ahead.
// B-frag = one 16B load/lane from Wt (L2-resident 409KB/kc chunk), prefetched 1 iter ahead.
__global__ __launch_bounds__(256) void gemm_reg_kernel(const int* __restrict__ x,
                                                       const unsigned short* __restrict__ embbf,
                                                       const unsigned short* __restrict__ Wt,
                                                       unsigned short* __restrict__ Cp) {
    const int tid  = threadIdx.x;
    const int lane = tid & 63;
    const int wv   = tid >> 6;
    const int m0   = blockIdx.x * BM;
    const int kc   = blockIdx.y;
    const int r16  = lane & 15;
    const int q    = lane >> 4;                        // 0..3: k-group within BK=32

    // per-lane A source pointers: row = m0+i*16+r16, position stream kc*100+q + 4*kt
    const int* xp[4]; bool av[4];
#pragma unroll
    for (int i = 0; i < 4; ++i) {
        int row = m0 + i * 16 + r16;
        av[i] = (row < MROWS);
        int rc = av[i] ? row : 0;
        int b = rc / TWIN, t = rc - b * TWIN;
        xp[i] = x + ((size_t)b * LSEQ + (size_t)t * KCONV + kc * PCH + q);
    }
    // per-lane B pointers: n = wv*64 + j*16 + r16, k-offset kc*800 + q*8 + 32*kt
    const unsigned short* bp[4];
#pragma unroll
    for (int j = 0; j < 4; ++j) {
        int n = wv * 64 + j * 16 + r16;
        bp[j] = Wt + ((size_t)n * KDIM + kc * KCH + q * 8);
    }

    floatx4 acc[4][4];
#pragma unroll
    for (int i = 0; i < 4; ++i)
#pragma unroll
        for (int j = 0; j < 4; ++j) acc[i][j] = floatx4{0.f, 0.f, 0.f, 0.f};

    bf16x8 af0[4], af1[4], bf0[4], bf1[4];
    int    xv0[4], xv1[4];

    // ---- prologue: frags for kt=0, x for kt=1 ----
#pragma unroll
    for (int i = 0; i < 4; ++i) xv0[i] = av[i] ? xp[i][0] : VOCABP;
#pragma unroll
    for (int i = 0; i < 4; ++i) af0[i] = *(const bf16x8*)(embbf + xv0[i] * 8);
#pragma unroll
    for (int j = 0; j < 4; ++j) bf0[j] = *(const bf16x8*)(bp[j]);
#pragma unroll
    for (int i = 0; i < 4; ++i) xv1[i] = av[i] ? xp[i][4] : VOCABP;

    // ---- main loop, unrolled x2 so ping-pong buffers are compile-time ----
    for (int kt2 = 0; kt2 < 12; ++kt2) {
        const int kt = kt2 * 2;
        // === body A (iteration kt, even) ===
        // prefetch frags for kt+1, x for kt+2
#pragma unroll
        for (int i = 0; i < 4; ++i) af1[i] = *(const bf16x8*)(embbf + xv1[i] * 8);
#pragma unroll
        for (int j = 0; j < 4; ++j) bf1[j] = *(const bf16x8*)(bp[j] + (kt + 1) * 32);
#pragma unroll
        for (int i = 0; i < 4; ++i) xv0[i] = av[i] ? xp[i][(kt + 2) * 4] : VOCABP;
#pragma unroll
        for (int i = 0; i < 4; ++i)
#pragma unroll
            for (int j = 0; j < 4; ++j)
                acc[i][j] = __builtin_amdgcn_mfma_f32_16x16x32_bf16(af0[i], bf0[j], acc[i][j], 0, 0, 0);
        // === body B (iteration kt+1, odd) ===
        // prefetch frags for kt+2, x for kt+3
#pragma unroll
        for (int i = 0; i < 4; ++i) af0[i] = *(const bf16x8*)(embbf + xv0[i] * 8);
#pragma unroll
        for (int j = 0; j < 4; ++j) bf0[j] = *(const bf16x8*)(bp[j] + (kt + 2) * 32);
        if (kt2 < 11) {
#pragma unroll
            for (int i = 0; i < 4; ++i) xv1[i] = av[i] ? xp[i][(kt + 3) * 4] : VOCABP;
        }
#pragma unroll
        for (int i = 0; i < 4; ++i)
#pragma unroll
            for (int j = 0; j < 4; ++j)
                acc[i][j] = __builtin_amdgcn_mfma_f32_16x16x32_bf16(af1[i], bf1[j], acc[i][j], 0, 0, 0);
    }
    // === tail (kt=24) ===
#pragma unroll
    for (int i = 0; i < 4; ++i)
#pragma unroll
        for (int j = 0; j < 4; ++j)
            acc[i][j] = __builtin_amdgcn_mfma_f32_16x16x32_bf16(af0[i], bf0[j], acc[i][j], 0, 0, 0);

    // ---- epilogue: Cp[kc][n][m] bf16; C/D layout col=lane&15, row=(lane>>4)*4+reg ----
    unsigned short* Cout = Cp + (size_t)kc * NDIM * MPAD;
#pragma unroll
    for (int i = 0; i < 4; ++i) {
        const int mb = m0 + i * 16 + q * 4;
#pragma unroll
        for (int j = 0; j < 4; ++j) {
            const int n = wv * 64 + j * 16 + r16;
            uint2 u;
            u.x = pack2(acc[i][j][0], acc[i][j][1]);
            u.y = pack2(acc[i][j][2], acc[i][j][3]);
            *(uint2*)(Cout + (size_t)n * MPAD + mb) = u;
        }
    }
}

// ---------------- kernel 3: split-sum + gate + max over t, one block per (o,b) ----------------
__global__ __launch_bounds__(256) void gate_kernel(const unsigned short* __restrict__ Cp,
                                                   const float* __restrict__ b1,
                                                   const float* __restrict__ b2,
                                                   float* __restrict__ pool) {
    const int o = blockIdx.x;                          // 0..127
    const int b = blockIdx.y;                          // 0..7
    const int t = threadIdx.x;                         // 0..255
    const float b1v = b1[o], b2v = b2[o];
    const size_t mb = (size_t)b * TWIN;
    const unsigned short* s1[SPLITK];
    const unsigned short* s2[SPLITK];
#pragma unroll
    for (int s = 0; s < SPLITK; ++s) {
        s1[s] = Cp + ((size_t)s * NDIM + o) * MPAD + mb;
        s2[s] = Cp + ((size_t)s * NDIM + o + COUT) * MPAD + mb;
    }
    float gmax = 0.0f;                                 // gated = relu*sigmoid >= 0
    for (int m = t; m < TWIN; m += 256) {              // stride-1 across lanes: coalesced
        float c1 = b1v, c2 = b2v;
#pragma unroll
        for (int s = 0; s < SPLITK; ++s) {
            c1 += bf2f(s1[s][m]);
            c2 += bf2f(s2[s][m]);
        }
        float g = fmaxf(c1, 0.0f) / (1.0f + __expf(-c2));
        gmax = fmaxf(gmax, g);
    }
    __shared__ float red[256];
    red[t] = gmax;
    __syncthreads();
#pragma unroll
    for (int s = 128; s > 0; s >>= 1) {
        if (t < s) red[t] = fmaxf(red[t], red[t + s]);
        __syncthreads();
    }
    if (t == 0) pool[b * COUT + o] = red[0];
}

// ---------------- kernel 4: dense head ----------------
__global__ __launch_bounds__(128) void head_kernel(const float* __restrict__ pool,
                                                   const float* __restrict__ wd1,
                                                   const float* __restrict__ bd1,
                                                   const float* __restrict__ wd2,
                                                   const float* __restrict__ bd2,
                                                   float* __restrict__ out) {
    __shared__ float red[BATCH][COUT];
    int j = threadIdx.x;                               // 0..127
    float wj = wd2[j];
#pragma unroll
    for (int b = 0; b < BATCH; ++b) {
        float s = bd1[j];
        for (int i = 0; i < COUT; ++i) s += pool[b * COUT + i] * wd1[j * COUT + i];
        red[b][j] = fmaxf(s, 0.0f) * wj;
    }
    __syncthreads();
    if (j < BATCH) {
        float s = 0.0f;
        for (int i = 0; i < COUT; ++i) s += red[j][i];
        out[j] = 1.0f / (1.0f + expf(-(s + bd2[0])));
    }
}

// ---------------- launch ----------------
extern "C" void kernel_launch(void* const* d_in, const int* in_sizes, int n_in,
                              void* d_out, int out_size, void* d_ws, size_t ws_size,
                              hipStream_t stream) {
    const int*   x   = (const int*)d_in[0];
    const float* emb = (const float*)d_in[1];
    const float* w1  = (const float*)d_in[2];
    const float* b1  = (const float*)d_in[3];
    const float* w2  = (const float*)d_in[4];
    const float* b2  = (const float*)d_in[5];
    const float* wd1 = (const float*)d_in[6];
    const float* bd1 = (const float*)d_in[7];
    const float* wd2 = (const float*)d_in[8];
    const float* bd2 = (const float*)d_in[9];
    float* out = (float*)d_out;

    unsigned short* Wt    = (unsigned short*)((char*)d_ws + WT_OFF);
    unsigned short* embbf = (unsigned short*)((char*)d_ws + EMB_OFF);
    unsigned short* Cp    = (unsigned short*)((char*)d_ws + CP_OFF);
    float*          pool  = (float*)((char*)d_ws + POOL_OFF);

    wprep_kernel<<<dim3(NDIM), dim3(256), 0, stream>>>(w1, w2, emb, Wt, embbf);
    gemm_reg_kernel<<<dim3(MPAD / BM, SPLITK), dim3(256), 0, stream>>>(x, embbf, Wt, Cp);
    gate_kernel<<<dim3(COUT, BATCH), dim3(256), 0, stream>>>(Cp, b1, b2, pool);
    head_kernel<<<dim3(1), dim3(128), 0, stream>>>(pool, wd1, bd1, wd2, bd2, out);
}